// Round 1
// baseline (1692.316 us; speedup 1.0000x reference)
//
#include <hip/hip_runtime.h>

// rAdjConv: out[dst] += x[src] / edge_div  over 64 features per edge.
// Round 0: correctness-first atomic scatter.
// 16 threads per edge; each thread handles one float4 (4 feats).

constexpr int D_FEAT = 64;

__global__ void radj_scatter_kernel(const float* __restrict__ x,
                                    const int* __restrict__ edge_src,
                                    const int* __restrict__ edge_dst,
                                    const float* __restrict__ edge_div,
                                    float* __restrict__ out,
                                    int nedges) {
    long long tid = (long long)blockIdx.x * blockDim.x + threadIdx.x;
    long long total = (long long)nedges * 16;
    if (tid >= total) return;

    int e  = (int)(tid >> 4);          // edge index
    int fg = (int)(tid & 15) << 2;     // feature group start (0,4,...,60)

    int s = edge_src[e];
    int d = edge_dst[e];
    float inv = 1.0f / edge_div[e];

    const float4 v = *reinterpret_cast<const float4*>(x + (long long)s * D_FEAT + fg);
    float* o = out + (long long)d * D_FEAT + fg;

    atomicAdd(o + 0, v.x * inv);
    atomicAdd(o + 1, v.y * inv);
    atomicAdd(o + 2, v.z * inv);
    atomicAdd(o + 3, v.w * inv);
}

extern "C" void kernel_launch(void* const* d_in, const int* in_sizes, int n_in,
                              void* d_out, int out_size, void* d_ws, size_t ws_size,
                              hipStream_t stream) {
    const float* x        = (const float*)d_in[0];
    const int*   edge_src = (const int*)d_in[1];
    const int*   edge_dst = (const int*)d_in[2];
    const float* edge_div = (const float*)d_in[3];
    float* out = (float*)d_out;

    int nedges = in_sizes[1];   // 2E

    // Output must be zeroed every call (harness poisons once, never re-zeroes).
    hipMemsetAsync(out, 0, (size_t)out_size * sizeof(float), stream);

    long long total = (long long)nedges * 16;
    int block = 256;
    long long grid = (total + block - 1) / block;

    radj_scatter_kernel<<<(int)grid, block, 0, stream>>>(
        x, edge_src, edge_dst, edge_div, out, nedges);
}

// Round 2
// 425.743 us; speedup vs baseline: 3.9750x; 3.9750x over previous
//
#include <hip/hip_runtime.h>

// rAdjConv: out[dst] += x[src] / edge_div over 64 features per edge.
// Round 2: scatter -> gather. Build dst-CSR on device (count, scan, fill),
// then one wave per node accumulates its incoming messages in registers.
// No float atomics in the feature pass.

constexpr int D_FEAT = 64;
constexpr int SCAN_B = 1024;   // elements (== threads) per scan block

// ---------- fallback (round-1 atomic scatter) ----------
__global__ void radj_scatter_kernel(const float* __restrict__ x,
                                    const int* __restrict__ edge_src,
                                    const int* __restrict__ edge_dst,
                                    const float* __restrict__ edge_div,
                                    float* __restrict__ out,
                                    int nedges) {
    long long tid = (long long)blockIdx.x * blockDim.x + threadIdx.x;
    long long total = (long long)nedges * 16;
    if (tid >= total) return;
    int e  = (int)(tid >> 4);
    int fg = (int)(tid & 15) << 2;
    int s = edge_src[e];
    int d = edge_dst[e];
    float inv = 1.0f / edge_div[e];
    const float4 v = *reinterpret_cast<const float4*>(x + (long long)s * D_FEAT + fg);
    float* o = out + (long long)d * D_FEAT + fg;
    atomicAdd(o + 0, v.x * inv);
    atomicAdd(o + 1, v.y * inv);
    atomicAdd(o + 2, v.z * inv);
    atomicAdd(o + 3, v.w * inv);
}

// ---------- CSR build ----------
__global__ void count_deg(const int* __restrict__ dst, int* __restrict__ deg, int n) {
    int gid = blockIdx.x * blockDim.x + threadIdx.x;
    if (gid < n) atomicAdd(&deg[dst[gid]], 1);
}

// Hillis-Steele inclusive scan over SCAN_B-sized blocks.
__global__ void scan_block(const int* __restrict__ in, int* __restrict__ incl,
                           int* __restrict__ bsums, int n) {
    __shared__ int tmp[SCAN_B];
    int gid = blockIdx.x * SCAN_B + threadIdx.x;
    int v = (gid < n) ? in[gid] : 0;
    tmp[threadIdx.x] = v;
    __syncthreads();
    for (int ofs = 1; ofs < SCAN_B; ofs <<= 1) {
        int t = (threadIdx.x >= ofs) ? tmp[threadIdx.x - ofs] : 0;
        __syncthreads();
        tmp[threadIdx.x] += t;
        __syncthreads();
    }
    if (gid < n) incl[gid] = tmp[threadIdx.x];
    if (bsums && threadIdx.x == SCAN_B - 1) bsums[blockIdx.x] = tmp[SCAN_B - 1];
}

// off[i] = exclusive prefix; cursor[i] = off[i]; off[n] = total.
__global__ void scan_finalize(const int* __restrict__ deg, const int* __restrict__ incl,
                              const int* __restrict__ bsums_incl,
                              int* __restrict__ off, int* __restrict__ cursor, int n) {
    int gid = blockIdx.x * SCAN_B + threadIdx.x;
    if (gid >= n) return;
    int boff = (blockIdx.x > 0) ? bsums_incl[blockIdx.x - 1] : 0;
    int d = deg[gid];
    int e = incl[gid] - d + boff;
    off[gid] = e;
    cursor[gid] = e;
    if (gid == n - 1) off[n] = e + d;
}

__global__ void fill_csr(const int* __restrict__ src, const int* __restrict__ dst,
                         const float* __restrict__ ediv, int* __restrict__ cursor,
                         int* __restrict__ csr_src, float* __restrict__ csr_w, int n) {
    int gid = blockIdx.x * blockDim.x + threadIdx.x;
    if (gid >= n) return;
    int d = dst[gid];
    int pos = atomicAdd(&cursor[d], 1);
    csr_src[pos] = src[gid];
    csr_w[pos] = 1.0f / ediv[gid];
}

// ---------- gather: one wave per node, lane = feature ----------
__global__ void gather_kernel(const float* __restrict__ x,
                              const int* __restrict__ off,
                              const int* __restrict__ csr_src,
                              const float* __restrict__ csr_w,
                              float* __restrict__ out, int nnodes) {
    int wid = (blockIdx.x * blockDim.x + threadIdx.x) >> 6;  // wave id = node id
    int lane = threadIdx.x & 63;
    if (wid >= nnodes) return;
    int beg = off[wid], end = off[wid + 1];
    float acc = 0.0f;
    for (int i = beg; i < end; ++i) {
        int s = csr_src[i];
        float w = csr_w[i];
        acc += x[(size_t)s * D_FEAT + lane] * w;
    }
    out[(size_t)wid * D_FEAT + lane] = acc;
}

extern "C" void kernel_launch(void* const* d_in, const int* in_sizes, int n_in,
                              void* d_out, int out_size, void* d_ws, size_t ws_size,
                              hipStream_t stream) {
    const float* x        = (const float*)d_in[0];
    const int*   edge_src = (const int*)d_in[1];
    const int*   edge_dst = (const int*)d_in[2];
    const float* edge_div = (const float*)d_in[3];
    float* out = (float*)d_out;

    int nedges = in_sizes[1];           // 2E
    int nnodes = out_size / D_FEAT;     // N_NODES

    // ws layout (ints/floats, 4B each)
    size_t needed = ((size_t)(4 * nnodes + 1 + 1024) + 2 * (size_t)nedges) * 4;
    if (ws_size < needed) {
        // fallback: atomic scatter
        hipMemsetAsync(out, 0, (size_t)out_size * sizeof(float), stream);
        long long total = (long long)nedges * 16;
        int block = 256;
        long long grid = (total + block - 1) / block;
        radj_scatter_kernel<<<(int)grid, block, 0, stream>>>(
            x, edge_src, edge_dst, edge_div, out, nedges);
        return;
    }

    int* deg     = (int*)d_ws;            // nnodes
    int* incl    = deg + nnodes;          // nnodes
    int* off     = incl + nnodes;         // nnodes + 1
    int* cursor  = off + nnodes + 1;      // nnodes
    int* bsums   = cursor + nnodes;       // up to 1024
    int* csr_src = bsums + 1024;          // nedges
    float* csr_w = (float*)(csr_src + nedges);  // nedges

    int nblk = (nnodes + SCAN_B - 1) / SCAN_B;  // 147 for 150K

    hipMemsetAsync(deg, 0, (size_t)nnodes * sizeof(int), stream);

    count_deg<<<(nedges + 255) / 256, 256, 0, stream>>>(edge_dst, deg, nedges);

    scan_block<<<nblk, SCAN_B, 0, stream>>>(deg, incl, bsums, nnodes);
    scan_block<<<1, SCAN_B, 0, stream>>>(bsums, bsums, nullptr, nblk);
    scan_finalize<<<nblk, SCAN_B, 0, stream>>>(deg, incl, bsums, off, cursor, nnodes);

    fill_csr<<<(nedges + 255) / 256, 256, 0, stream>>>(
        edge_src, edge_dst, edge_div, cursor, csr_src, csr_w, nedges);

    long long gthreads = (long long)nnodes * 64;
    gather_kernel<<<(int)((gthreads + 255) / 256), 256, 0, stream>>>(
        x, off, csr_src, csr_w, out, nnodes);
}

// Round 3
// 343.295 us; speedup vs baseline: 4.9296x; 1.2402x over previous
//
#include <hip/hip_runtime.h>

// rAdjConv: out[dst] += x[src] / edge_div over 64 features per edge.
// Round 3: exploit edge_div = sqrt(deg[s])*sqrt(deg[d]) (R=0.5, deg = dst-counts
// of the symmetric edge list). out[d] = alpha[d] * sum_s alpha[s]*x[s],
// alpha = rsqrt(deg). CSR stores only src indices; gather unrolled 4x for MLP.

constexpr int D_FEAT = 64;
constexpr int SCAN_B = 1024;

// ---------- fallback (round-1 atomic scatter) ----------
__global__ void radj_scatter_kernel(const float* __restrict__ x,
                                    const int* __restrict__ edge_src,
                                    const int* __restrict__ edge_dst,
                                    const float* __restrict__ edge_div,
                                    float* __restrict__ out,
                                    int nedges) {
    long long tid = (long long)blockIdx.x * blockDim.x + threadIdx.x;
    long long total = (long long)nedges * 16;
    if (tid >= total) return;
    int e  = (int)(tid >> 4);
    int fg = (int)(tid & 15) << 2;
    int s = edge_src[e];
    int d = edge_dst[e];
    float inv = 1.0f / edge_div[e];
    const float4 v = *reinterpret_cast<const float4*>(x + (long long)s * D_FEAT + fg);
    float* o = out + (long long)d * D_FEAT + fg;
    atomicAdd(o + 0, v.x * inv);
    atomicAdd(o + 1, v.y * inv);
    atomicAdd(o + 2, v.z * inv);
    atomicAdd(o + 3, v.w * inv);
}

// ---------- CSR build ----------
__global__ void count_deg(const int* __restrict__ dst, int* __restrict__ deg, int n) {
    int gid = blockIdx.x * blockDim.x + threadIdx.x;
    if (gid < n) atomicAdd(&deg[dst[gid]], 1);
}

__global__ void scan_block(const int* __restrict__ in, int* __restrict__ incl,
                           int* __restrict__ bsums, int n) {
    __shared__ int tmp[SCAN_B];
    int gid = blockIdx.x * SCAN_B + threadIdx.x;
    int v = (gid < n) ? in[gid] : 0;
    tmp[threadIdx.x] = v;
    __syncthreads();
    for (int ofs = 1; ofs < SCAN_B; ofs <<= 1) {
        int t = (threadIdx.x >= ofs) ? tmp[threadIdx.x - ofs] : 0;
        __syncthreads();
        tmp[threadIdx.x] += t;
        __syncthreads();
    }
    if (gid < n) incl[gid] = tmp[threadIdx.x];
    if (bsums && threadIdx.x == SCAN_B - 1) bsums[blockIdx.x] = tmp[SCAN_B - 1];
}

// off/cursor = exclusive prefix; alpha = rsqrt(deg); off[n] = total.
__global__ void scan_finalize(const int* __restrict__ deg, const int* __restrict__ incl,
                              const int* __restrict__ bsums_incl,
                              int* __restrict__ off, int* __restrict__ cursor,
                              float* __restrict__ alpha, int n) {
    int gid = blockIdx.x * SCAN_B + threadIdx.x;
    if (gid >= n) return;
    int boff = (blockIdx.x > 0) ? bsums_incl[blockIdx.x - 1] : 0;
    int d = deg[gid];
    int e = incl[gid] - d + boff;
    off[gid] = e;
    cursor[gid] = e;
    alpha[gid] = rsqrtf(fmaxf((float)d, 1.0f));
    if (gid == n - 1) off[n] = e + d;
}

__global__ void fill_csr(const int* __restrict__ src, const int* __restrict__ dst,
                         int* __restrict__ cursor, int* __restrict__ csr_src, int n) {
    int gid = blockIdx.x * blockDim.x + threadIdx.x;
    if (gid >= n) return;
    int pos = atomicAdd(&cursor[dst[gid]], 1);
    csr_src[pos] = src[gid];
}

// ---------- gather: one wave per node, lane = feature, 4-deep MLP ----------
__global__ void gather_kernel(const float* __restrict__ x,
                              const float* __restrict__ alpha,
                              const int* __restrict__ off,
                              const int* __restrict__ csr_src,
                              float* __restrict__ out, int nnodes) {
    int wid = (blockIdx.x * blockDim.x + threadIdx.x) >> 6;  // node id
    int lane = threadIdx.x & 63;
    if (wid >= nnodes) return;
    int beg = off[wid], end = off[wid + 1];
    float acc = 0.0f;
    int i = beg;
    for (; i + 4 <= end; i += 4) {
        int s0 = csr_src[i + 0];
        int s1 = csr_src[i + 1];
        int s2 = csr_src[i + 2];
        int s3 = csr_src[i + 3];
        float a0 = alpha[s0], a1 = alpha[s1], a2 = alpha[s2], a3 = alpha[s3];
        float v0 = x[(size_t)s0 * D_FEAT + lane];
        float v1 = x[(size_t)s1 * D_FEAT + lane];
        float v2 = x[(size_t)s2 * D_FEAT + lane];
        float v3 = x[(size_t)s3 * D_FEAT + lane];
        acc += v0 * a0;
        acc += v1 * a1;
        acc += v2 * a2;
        acc += v3 * a3;
    }
    for (; i < end; ++i) {
        int s = csr_src[i];
        acc += x[(size_t)s * D_FEAT + lane] * alpha[s];
    }
    out[(size_t)wid * D_FEAT + lane] = acc * alpha[wid];
}

extern "C" void kernel_launch(void* const* d_in, const int* in_sizes, int n_in,
                              void* d_out, int out_size, void* d_ws, size_t ws_size,
                              hipStream_t stream) {
    const float* x        = (const float*)d_in[0];
    const int*   edge_src = (const int*)d_in[1];
    const int*   edge_dst = (const int*)d_in[2];
    const float* edge_div = (const float*)d_in[3];
    float* out = (float*)d_out;

    int nedges = in_sizes[1];           // 2E
    int nnodes = out_size / D_FEAT;     // N_NODES

    size_t needed = ((size_t)(5 * nnodes + 1 + 1024) + (size_t)nedges) * 4;
    if (ws_size < needed) {
        hipMemsetAsync(out, 0, (size_t)out_size * sizeof(float), stream);
        long long total = (long long)nedges * 16;
        int block = 256;
        long long grid = (total + block - 1) / block;
        radj_scatter_kernel<<<(int)grid, block, 0, stream>>>(
            x, edge_src, edge_dst, edge_div, out, nedges);
        return;
    }

    int*   deg     = (int*)d_ws;              // nnodes
    int*   incl    = deg + nnodes;            // nnodes
    int*   off     = incl + nnodes;           // nnodes + 1
    int*   cursor  = off + nnodes + 1;        // nnodes
    float* alpha   = (float*)(cursor + nnodes);  // nnodes
    int*   bsums   = (int*)(alpha + nnodes);  // 1024
    int*   csr_src = bsums + 1024;            // nedges

    int nblk = (nnodes + SCAN_B - 1) / SCAN_B;

    hipMemsetAsync(deg, 0, (size_t)nnodes * sizeof(int), stream);

    count_deg<<<(nedges + 255) / 256, 256, 0, stream>>>(edge_dst, deg, nedges);

    scan_block<<<nblk, SCAN_B, 0, stream>>>(deg, incl, bsums, nnodes);
    scan_block<<<1, SCAN_B, 0, stream>>>(bsums, bsums, nullptr, nblk);
    scan_finalize<<<nblk, SCAN_B, 0, stream>>>(deg, incl, bsums, off, cursor, alpha, nnodes);

    fill_csr<<<(nedges + 255) / 256, 256, 0, stream>>>(
        edge_src, edge_dst, cursor, csr_src, nedges);

    long long gthreads = (long long)nnodes * 64;
    gather_kernel<<<(int)((gthreads + 255) / 256), 256, 0, stream>>>(
        x, alpha, off, csr_src, out, nnodes);
}